// Round 5
// baseline (148.642 us; speedup 1.0000x reference)
//
#include <hip/hip_runtime.h>

#define BSZ 512
#define EPSF 1e-5f
#define KT   32          // k-chunk per tile-job
#define NS   16          // split-k factor (NS*KT = 512)
#define TR   128         // tile rows
#define TC   64          // tile cols
#define ASTR 132         // As stride: mult of 4 (16B-aligned b128), mod 32 = 4
#define BSTR 68          // Bs stride: mult of 4, mod 32 = 4
#define NBLK 512

// ws layout (floats): [0] phase-barrier counter (int), [1] finale counter (int),
// [8 .. 8+3*512) per-anchor partials, [2048 ..) P[NS][512][512]
#define WS_PARTIAL 8
#define WS_P       2048

__device__ __forceinline__ float dist_xform(float v) {
    v = fmaxf(v, 0.0f);
    float z = (v == 0.0f) ? 1.0f : 0.0f;   // zmask per reference
    v = sqrtf(v + z * EPSF) + EPSF;
    return v * (1.0f - z);
}

// One kernel: phase 1 = split-k partial squared distances (128x64 tile, 8x4
// micro); device-wide counter barrier; phase 2 = per-anchor triplet sums with
// decoupled last-block finale. 512 blocks, <=128 VGPR -> >=4 blocks/CU
// capacity, so all 512 are co-resident (spin barrier is safe).
__global__ __launch_bounds__(256, 4) void unified_kernel(const float* __restrict__ E,
                                                         const int* __restrict__ labels,
                                                         float* __restrict__ ws,
                                                         float* __restrict__ out) {
    const int tid = threadIdx.x;
    const int b   = blockIdx.x;

    __shared__ __align__(16) float As[KT][ASTR];   // transposed: As[k][row]
    __shared__ __align__(16) float Bs[KT][BSTR];
    __shared__ float drow[BSZ];
    __shared__ int   lab[BSZ];
    __shared__ int   poslist[BSZ];
    __shared__ int   npos_s;
    __shared__ float wsum[4];
    __shared__ int   wcnt[4];
    __shared__ int   is_last;

    // ---------------- Phase 1: P[s][i][j] partial squared distances ----------
    {
        const int bi = (b & 3) * TR;            // 4 row-tiles
        const int bj = ((b >> 2) & 7) * TC;     // 8 col-tiles
        const int k0 = (b >> 5) * KT;           // 16 k-chunks

        // Stage transposed. Global float4 coalesced; scalar LDS writes (~4-way).
        const int r0 = tid >> 3;          // 0..31
        const int kc = (tid & 7) * 4;     // 0,4,..,28
#pragma unroll
        for (int p = 0; p < 4; ++p) {
            const int row = p * 32 + r0;
            float4 v = *(const float4*)(E + (size_t)(bi + row) * BSZ + k0 + kc);
            As[kc  ][row] = v.x; As[kc+1][row] = v.y; As[kc+2][row] = v.z; As[kc+3][row] = v.w;
        }
#pragma unroll
        for (int p = 0; p < 2; ++p) {
            const int row = p * 32 + r0;
            float4 v = *(const float4*)(E + (size_t)(bj + row) * BSZ + k0 + kc);
            Bs[kc  ][row] = v.x; Bs[kc+1][row] = v.y; Bs[kc+2][row] = v.z; Bs[kc+3][row] = v.w;
        }
        __syncthreads();

        const int tx = tid & 15;          // col group: j = bj + tx*4
        const int ty = tid >> 4;          // row group: i = bi + ty*8
        float acc[8][4];
#pragma unroll
        for (int r = 0; r < 8; ++r)
#pragma unroll
            for (int c = 0; c < 4; ++c) acc[r][c] = 0.0f;

#pragma unroll 4
        for (int kk = 0; kk < KT; ++kk) {
            // A: 4 addrs/wave (x16 broadcast) -> conflict-free. B: 2-way (free).
            float4 A0 = *(const float4*)&As[kk][ty * 8];
            float4 A1 = *(const float4*)&As[kk][ty * 8 + 4];
            float4 B0 = *(const float4*)&Bs[kk][tx * 4];
            float ar[8] = {A0.x, A0.y, A0.z, A0.w, A1.x, A1.y, A1.z, A1.w};
            float br[4] = {B0.x, B0.y, B0.z, B0.w};
#pragma unroll
            for (int r = 0; r < 8; ++r)
#pragma unroll
                for (int c = 0; c < 4; ++c) {
                    float d = ar[r] - br[c];
                    acc[r][c] = fmaf(d, d, acc[r][c]);
                }
        }

        float* Pp = ws + WS_P + (size_t)(b >> 5) * BSZ * BSZ;
#pragma unroll
        for (int r = 0; r < 8; ++r) {   // 16 lanes x float4 = 256B contiguous
            float4 v = {acc[r][0], acc[r][1], acc[r][2], acc[r][3]};
            *(float4*)(Pp + (size_t)(bi + ty * 8 + r) * BSZ + bj + tx * 4) = v;
        }
    }

    // ---------------- Device-wide barrier (all 512 blocks co-resident) -------
    __syncthreads();   // drains all threads' stores (vmcnt(0) before s_barrier)
    unsigned int* cnt = (unsigned int*)ws;
    if (tid == 0) {
        __threadfence();                  // release: write back L2 (cross-XCD)
        atomicAdd(&cnt[0], 1u);
        while (__hip_atomic_load(&cnt[0], __ATOMIC_ACQUIRE,
                                 __HIP_MEMORY_SCOPE_AGENT) < NBLK) {
            __builtin_amdgcn_s_sleep(2);
        }
        __threadfence();                  // acquire: invalidate stale lines
    }
    __syncthreads();

    // ---------------- Phase 2: triplet sums for anchor a = b -----------------
    const int a = b;
    if (tid == 0) npos_s = 0;
    for (int t = tid; t < BSZ; t += 256) lab[t] = labels[t];

    const float* P = ws + WS_P;
    if (tid < 128) {   // 128 threads x float4 = 512 cols; sum NS chunk partials
        float4 s4 = {0.f, 0.f, 0.f, 0.f};
#pragma unroll
        for (int s = 0; s < NS; ++s) {
            float4 v = *(const float4*)(P + ((size_t)s * BSZ + a) * BSZ + tid * 4);
            s4.x += v.x; s4.y += v.y; s4.z += v.z; s4.w += v.w;
        }
        drow[tid * 4 + 0] = dist_xform(s4.x);
        drow[tid * 4 + 1] = dist_xform(s4.y);
        drow[tid * 4 + 2] = dist_xform(s4.z);
        drow[tid * 4 + 3] = dist_xform(s4.w);
    }
    __syncthreads();

    const int la = lab[a];
    for (int t = tid; t < BSZ; t += 256) {
        if (lab[t] == la && t != a) {
            int idx = atomicAdd(&npos_s, 1);
            poslist[idx] = t;
        }
    }
    __syncthreads();

    const int npos = npos_s;
    const int nneg = BSZ - 1 - npos;
    float sum = 0.0f;
    int   cnt2 = 0;
    const int total = npos * BSZ;
    for (int idx = tid; idx < total; idx += 256) {
        const int p = poslist[idx >> 9];   // broadcast within wave
        const int n = idx & (BSZ - 1);     // consecutive -> conflict-free
        if (lab[n] != la) {
            const float v = drow[p] - drow[n];   // margin = 0
            if (v > 0.0f)  sum += v;
            if (v > 1e-5f) cnt2++;
        }
    }
#pragma unroll
    for (int off = 32; off > 0; off >>= 1) {
        sum  += __shfl_down(sum, off);
        cnt2 += __shfl_down(cnt2, off);
    }
    const int wave = tid >> 6, lane = tid & 63;
    if (lane == 0) { wsum[wave] = sum; wcnt[wave] = cnt2; }
    __syncthreads();

    float* partial = ws + WS_PARTIAL;
    if (tid == 0) {
        partial[a]           = wsum[0] + wsum[1] + wsum[2] + wsum[3];
        partial[BSZ + a]     = (float)(wcnt[0] + wcnt[1] + wcnt[2] + wcnt[3]);
        partial[2*BSZ + a]   = (float)npos * (float)nneg;
        __threadfence();                        // release partials device-wide
        int old = atomicAdd((int*)&cnt[1], 1);
        is_last = (old == NBLK - 1) ? 1 : 0;
    }
    __syncthreads();

    if (is_last) {   // exactly one block runs the finale
        __threadfence();
        float s = partial[tid]         + partial[tid + 256];
        float c = partial[BSZ + tid]   + partial[BSZ + tid + 256];
        float v = partial[2*BSZ + tid] + partial[2*BSZ + tid + 256];
#pragma unroll
        for (int off = 32; off > 0; off >>= 1) {
            s += __shfl_down(s, off);
            c += __shfl_down(c, off);
            v += __shfl_down(v, off);
        }
        if (lane == 0) { wsum[wave] = s; wcnt[wave] = (int)c; drow[wave] = v; }
        __syncthreads();
        if (tid == 0) {
            float S = wsum[0] + wsum[1] + wsum[2] + wsum[3];
            float C = (float)(wcnt[0] + wcnt[1] + wcnt[2] + wcnt[3]);
            float V = drow[0] + drow[1] + drow[2] + drow[3];
            out[0] = S / (C + 1e-5f);   // loss
            out[1] = C / (V + 1e-5f);   // fraction_positive
        }
    }
}

extern "C" void kernel_launch(void* const* d_in, const int* in_sizes, int n_in,
                              void* d_out, int out_size, void* d_ws, size_t ws_size,
                              hipStream_t stream) {
    const float* E      = (const float*)d_in[0];   // embeddings [512,512] fp32
    const int*   labels = (const int*)d_in[1];     // labels [512]
    float* out = (float*)d_out;
    float* ws  = (float*)d_ws;

    hipMemsetAsync(ws, 0, 8, stream);   // zero both counters (graph-capturable)
    unified_kernel<<<NBLK, 256, 0, stream>>>(E, labels, ws, out);
}

// Round 6
// 79.346 us; speedup vs baseline: 1.8733x; 1.8733x over previous
//
#include <hip/hip_runtime.h>

#define BSZ 512
#define EPSF 1e-5f
#define KT   64          // k-chunk per block
#define NS   8           // split-k factor (NS*KT = 512)
#define TT   64          // square tile (rows = cols = 64)
#define LSTR 68          // LDS row stride: mult of 4 (16B-aligned b128), mod 32 = 4

// ws layout (floats): [0..8) spare, [8 .. 8+3*512) per-anchor partials,
// [2048 ..) P[NS][512][512]  (8 MB)
#define WS_PARTIAL 8
#define WS_P       2048

__device__ __forceinline__ float dist_xform(float v) {
    v = fmaxf(v, 0.0f);
    float z = (v == 0.0f) ? 1.0f : 0.0f;   // zmask per reference
    v = sqrtf(v + z * EPSF) + EPSF;
    return v * (1.0f - z);
}

// ---- Kernel 1: partial squared distances. 64x64 tile, 4x4 micro, split-k. ----
// P[s][i][j] = sum_{k in chunk s} (E[i,k]-E[j,k])^2
// grid (8,8,8) = 512 blocks x 256 thr -> 2 blocks/CU, 2 waves/SIMD.
__global__ __launch_bounds__(256) void dsq_kernel(const float* __restrict__ E,
                                                  float* __restrict__ ws) {
    __shared__ __align__(16) float As[KT][LSTR];   // transposed: As[k][row]
    __shared__ __align__(16) float Bs[KT][LSTR];
    const int tid = threadIdx.x;
    const int bj = blockIdx.x * TT;
    const int bi = blockIdx.y * TT;
    const int k0 = blockIdx.z * KT;

    // Stage transposed. Global float4 coalesced (16 thr x 16B = 256B rows).
    {
        const int r0 = tid >> 4;          // 0..15
        const int kc = (tid & 15) * 4;    // 0,4,..,60
#pragma unroll
        for (int p = 0; p < 4; ++p) {
            const int row = p * 16 + r0;
            float4 va = *(const float4*)(E + (size_t)(bi + row) * BSZ + k0 + kc);
            float4 vb = *(const float4*)(E + (size_t)(bj + row) * BSZ + k0 + kc);
            As[kc  ][row] = va.x; As[kc+1][row] = va.y; As[kc+2][row] = va.z; As[kc+3][row] = va.w;
            Bs[kc  ][row] = vb.x; Bs[kc+1][row] = vb.y; Bs[kc+2][row] = vb.z; Bs[kc+3][row] = vb.w;
        }
    }
    __syncthreads();

    const int tx = tid & 15;          // col group: j = bj + tx*4
    const int ty = tid >> 4;          // row group: i = bi + ty*4
    float acc[4][4];
#pragma unroll
    for (int r = 0; r < 4; ++r)
#pragma unroll
        for (int c = 0; c < 4; ++c) acc[r][c] = 0.0f;

#pragma unroll 8
    for (int kk = 0; kk < KT; ++kk) {
        // A: 4 addrs/wave (x16 broadcast), banks 4*ty distinct -> conflict-free.
        // B: 16 addrs/wave, banks 4*tx -> 2-way (free per m136).
        float4 A0 = *(const float4*)&As[kk][ty * 4];
        float4 B0 = *(const float4*)&Bs[kk][tx * 4];
        float ar[4] = {A0.x, A0.y, A0.z, A0.w};
        float br[4] = {B0.x, B0.y, B0.z, B0.w};
#pragma unroll
        for (int r = 0; r < 4; ++r)
#pragma unroll
            for (int c = 0; c < 4; ++c) {
                float d = ar[r] - br[c];
                acc[r][c] = fmaf(d, d, acc[r][c]);
            }
    }

    float* Pp = ws + WS_P + (size_t)blockIdx.z * BSZ * BSZ;
#pragma unroll
    for (int r = 0; r < 4; ++r) {   // 16 lanes x float4 = 256B contiguous per row
        float4 v = {acc[r][0], acc[r][1], acc[r][2], acc[r][3]};
        *(float4*)(Pp + (size_t)(bi + ty * 4 + r) * BSZ + bj + tx * 4) = v;
    }
}

// ---- Kernel 2: per-anchor triplet sums (sums NS chunk partials + xform) ----
__global__ __launch_bounds__(256) void triplet_kernel(const int* __restrict__ labels,
                                                      const float* __restrict__ ws,
                                                      float* __restrict__ partial) {
    const int a = blockIdx.x;
    const int tid = threadIdx.x;
    __shared__ float drow[BSZ];
    __shared__ int   lab[BSZ];
    __shared__ int   poslist[BSZ];
    __shared__ int   npos_s;
    __shared__ float wsum[4];
    __shared__ int   wcnt[4];

    if (tid == 0) npos_s = 0;
    for (int t = tid; t < BSZ; t += 256) lab[t] = labels[t];

    const float* P = ws + WS_P;
    {   // 256 threads x float2 = 512 cols; sum the NS chunk partials
        float2 s2 = {0.f, 0.f};
#pragma unroll
        for (int s = 0; s < NS; ++s) {
            float2 v = *(const float2*)(P + ((size_t)s * BSZ + a) * BSZ + tid * 2);
            s2.x += v.x; s2.y += v.y;
        }
        drow[tid * 2 + 0] = dist_xform(s2.x);
        drow[tid * 2 + 1] = dist_xform(s2.y);
    }
    __syncthreads();

    const int la = lab[a];
    for (int t = tid; t < BSZ; t += 256) {
        if (lab[t] == la && t != a) {
            int idx = atomicAdd(&npos_s, 1);
            poslist[idx] = t;
        }
    }
    __syncthreads();

    const int npos = npos_s;
    const int nneg = BSZ - 1 - npos;
    float sum = 0.0f;
    int   cnt = 0;
    const int total = npos * BSZ;
    for (int idx = tid; idx < total; idx += 256) {
        const int p = poslist[idx >> 9];   // broadcast within wave
        const int n = idx & (BSZ - 1);     // consecutive -> conflict-free
        if (lab[n] != la) {
            const float v = drow[p] - drow[n];   // margin = 0
            if (v > 0.0f)  sum += v;
            if (v > 1e-5f) cnt++;
        }
    }
#pragma unroll
    for (int off = 32; off > 0; off >>= 1) {
        sum += __shfl_down(sum, off);
        cnt += __shfl_down(cnt, off);
    }
    const int wave = tid >> 6, lane = tid & 63;
    if (lane == 0) { wsum[wave] = sum; wcnt[wave] = cnt; }
    __syncthreads();
    if (tid == 0) {
        partial[a]           = wsum[0] + wsum[1] + wsum[2] + wsum[3];
        partial[BSZ + a]     = (float)(wcnt[0] + wcnt[1] + wcnt[2] + wcnt[3]);
        partial[2*BSZ + a]   = (float)npos * (float)nneg;
    }
}

// ---- Kernel 3: final reduce + scalar epilogue ----
__global__ __launch_bounds__(256) void final_kernel(const float* __restrict__ partial,
                                                    float* __restrict__ out) {
    const int tid = threadIdx.x;
    float s = partial[tid]         + partial[tid + 256];
    float c = partial[BSZ + tid]   + partial[BSZ + tid + 256];
    float v = partial[2*BSZ + tid] + partial[2*BSZ + tid + 256];
#pragma unroll
    for (int off = 32; off > 0; off >>= 1) {
        s += __shfl_down(s, off);
        c += __shfl_down(c, off);
        v += __shfl_down(v, off);
    }
    __shared__ float ws_[4], wc[4], wv[4];
    const int wave = tid >> 6, lane = tid & 63;
    if (lane == 0) { ws_[wave] = s; wc[wave] = c; wv[wave] = v; }
    __syncthreads();
    if (tid == 0) {
        float S = ws_[0] + ws_[1] + ws_[2] + ws_[3];
        float C = wc[0] + wc[1] + wc[2] + wc[3];
        float V = wv[0] + wv[1] + wv[2] + wv[3];
        out[0] = S / (C + 1e-5f);   // loss
        out[1] = C / (V + 1e-5f);   // fraction_positive
    }
}

extern "C" void kernel_launch(void* const* d_in, const int* in_sizes, int n_in,
                              void* d_out, int out_size, void* d_ws, size_t ws_size,
                              hipStream_t stream) {
    const float* E      = (const float*)d_in[0];   // embeddings [512,512] fp32
    const int*   labels = (const int*)d_in[1];     // labels [512]
    float* out = (float*)d_out;
    float* ws  = (float*)d_ws;
    float* partial = ws + WS_PARTIAL;

    dsq_kernel<<<dim3(8, 8, NS), 256, 0, stream>>>(E, ws);
    triplet_kernel<<<BSZ, 256, 0, stream>>>(labels, ws, partial);
    final_kernel<<<1, 256, 0, stream>>>(partial, out);
}